// Round 7
// baseline (39.256 us; speedup 1.0000x reference)
//
#include <hip/hip_runtime.h>

typedef float v8f __attribute__((ext_vector_type(8)));

#define NPTS   8192
#define BLOCK  256
#define CHUNKS 64
#define JT     (NPTS / CHUNKS)       // 128 j's per block-chunk

// ws layout (floats): X[NPTS] | Y[NPTS] | Z[NPTS] | partials[CHUNKS][NPTS][3]
#define WS_POFF (3 * NPTS)

// Pre-pass: AoS pos[i][3] -> SoA X/Y/Z so the hot loop can batch-load
// 8 consecutive j-coordinates with ONE uniform 32-byte load per array.
__global__ __launch_bounds__(BLOCK) void soa_pack(
    const float* __restrict__ pos,
    float* __restrict__ X, float* __restrict__ Y, float* __restrict__ Z)
{
    const int t = blockIdx.x * BLOCK + threadIdx.x;
    X[t] = pos[t * 3 + 0];
    Y[t] = pos[t * 3 + 1];
    Z[t] = pos[t * 3 + 2];
}

// Phase 1: block (bx, by) computes partial forces for its 256 i's over
// j in [by*JT, (by+1)*JT). j-loads are block-uniform 8-wide vectors:
// 3 loads per 8 pairs (0.375 mem-ops/pair vs 1.5 before) — if the scalar
// path was the stall (VALUBusy was only 32%), this is the 4x relief.
__global__ __launch_bounds__(BLOCK) void nbody_partial(
    const float* __restrict__ X, const float* __restrict__ Y,
    const float* __restrict__ Z, float* __restrict__ part)
{
    const int tid = threadIdx.x;
    const int i   = blockIdx.x * BLOCK + tid;
    const int g0  = blockIdx.y * (JT / 8);     // base 8-j group index

    const float xi = X[i], yi = Y[i], zi = Z[i];
    float fx = 0.0f, fy = 0.0f, fz = 0.0f;

    const v8f* __restrict__ X8 = (const v8f*)X;
    const v8f* __restrict__ Y8 = (const v8f*)Y;
    const v8f* __restrict__ Z8 = (const v8f*)Z;

#define PAIR(px, py, pz)                                                    \
    {                                                                       \
        const float dx = xi - (px);                                         \
        const float dy = yi - (py);                                         \
        const float dz = zi - (pz);                                         \
        const float r2  = fmaf(dz, dz, fmaf(dy, dy, fmaf(dx, dx, 1e-12f))); \
        const float ir  = __builtin_amdgcn_rsqf(r2);                        \
        const float ir3 = ir * ir * ir;                                     \
        fx = fmaf(dx, ir3, fx);                                             \
        fy = fmaf(dy, ir3, fy);                                             \
        fz = fmaf(dz, ir3, fz);                                             \
    }

#pragma unroll 4
    for (int g = 0; g < JT / 8; ++g) {
        const int u = g0 + g;                  // uniform address
        const v8f xg = X8[u];                  // 32B batched uniform load
        const v8f yg = Y8[u];
        const v8f zg = Z8[u];
#pragma unroll
        for (int k = 0; k < 8; ++k)            // constant k -> free extracts
            PAIR(xg[k], yg[k], zg[k]);
    }
#undef PAIR

    float* o = part + ((size_t)blockIdx.y * NPTS + i) * 3;
    o[0] = fx; o[1] = fy; o[2] = fz;
}

// Phase 2: out[e] = sum over chunks. float4-vectorized, fully coalesced.
__global__ __launch_bounds__(BLOCK) void nbody_reduce(
    const float4* __restrict__ part, float4* __restrict__ out)
{
    const int e = blockIdx.x * BLOCK + threadIdx.x;   // float4 index, 0..6143
    float4 s = make_float4(0.f, 0.f, 0.f, 0.f);
#pragma unroll 8
    for (int ch = 0; ch < CHUNKS; ++ch) {
        const float4 v = part[(size_t)ch * (NPTS * 3 / 4) + e];
        s.x += v.x; s.y += v.y; s.z += v.z; s.w += v.w;
    }
    out[e] = s;
}

extern "C" void kernel_launch(void* const* d_in, const int* in_sizes, int n_in,
                              void* d_out, int out_size, void* d_ws, size_t ws_size,
                              hipStream_t stream)
{
    const float* pos = (const float*)d_in[0];
    float* wsf = (float*)d_ws;
    float* X = wsf;
    float* Y = wsf + NPTS;
    float* Z = wsf + 2 * NPTS;
    float* part = wsf + WS_POFF;

    soa_pack<<<dim3(NPTS / BLOCK), dim3(BLOCK), 0, stream>>>(pos, X, Y, Z);

    dim3 grid1(NPTS / BLOCK, CHUNKS);   // 32 x 64 = 2048 blocks, 8/CU
    nbody_partial<<<grid1, dim3(BLOCK), 0, stream>>>(X, Y, Z, part);

    dim3 grid2(NPTS * 3 / 4 / BLOCK);   // 24 blocks
    nbody_reduce<<<grid2, dim3(BLOCK), 0, stream>>>((const float4*)part,
                                                    (float4*)d_out);
}

// Round 8
// 33.945 us; speedup vs baseline: 1.1565x; 1.1565x over previous
//
#include <hip/hip_runtime.h>

#define NPTS   8192
#define BLOCK  256
#define CHUNKS 64
#define JT     (NPTS / CHUNKS)   // 128 j's per block-chunk

// Phase 1: block (bx, by) computes, for its 256 i's, the partial force over
// j in [by*JT, (by+1)*JT); coalesced stores to ws, no atomics.
// R7 change vs R3 (minimal diff): w = rcp(r2)*rsq(r2) instead of rsq^3 —
// moves 2 muls off the main VALU pipe into 1 extra (independent) trans op.
__global__ __launch_bounds__(BLOCK) void nbody_partial(
    const float* __restrict__ pos, float* __restrict__ ws)
{
    const int tid = threadIdx.x;
    const int i   = blockIdx.x * BLOCK + tid;
    const int j0  = blockIdx.y * JT;

    const float xi = pos[i * 3 + 0];
    const float yi = pos[i * 3 + 1];
    const float zi = pos[i * 3 + 2];

    float fx = 0.0f, fy = 0.0f, fz = 0.0f;

    const float4* __restrict__ pos4 = (const float4*)pos;

#define PAIR(px, py, pz)                                                    \
    {                                                                       \
        const float dx = xi - (px);                                         \
        const float dy = yi - (py);                                         \
        const float dz = zi - (pz);                                         \
        const float r2  = fmaf(dz, dz, fmaf(dy, dy, fmaf(dx, dx, 1e-12f))); \
        /* r^-3 = r^-2 * r^-1; rcp and rsq are independent -> overlap */    \
        const float w = __builtin_amdgcn_rcpf(r2)                           \
                      * __builtin_amdgcn_rsqf(r2);                          \
        fx = fmaf(dx, w, fx);                                               \
        fy = fmaf(dy, w, fy);                                               \
        fz = fmaf(dz, w, fz);                                               \
    }

    // 4 points per 3 float4 loads (block-uniform addresses, L1/L2-broadcast).
#pragma unroll 4
    for (int g = 0; g < JT / 4; ++g) {
        const int base = (j0 / 4 + g) * 3;       // float4 index
        const float4 a = pos4[base + 0];
        const float4 b = pos4[base + 1];
        const float4 c = pos4[base + 2];
        PAIR(a.x, a.y, a.z);
        PAIR(a.w, b.x, b.y);
        PAIR(b.z, b.w, c.x);
        PAIR(c.y, c.z, c.w);
    }
#undef PAIR

    float* o = ws + ((size_t)blockIdx.y * NPTS + i) * 3;
    o[0] = fx; o[1] = fy; o[2] = fz;
}

// Phase 2: out[e] = sum over chunks of ws[ch][e]. Fully coalesced.
__global__ __launch_bounds__(BLOCK) void nbody_reduce(
    const float* __restrict__ ws, float* __restrict__ out)
{
    const int e = blockIdx.x * BLOCK + threadIdx.x;   // 0 .. NPTS*3-1
    float s = 0.0f;
#pragma unroll 16
    for (int ch = 0; ch < CHUNKS; ++ch)
        s += ws[(size_t)ch * NPTS * 3 + e];
    out[e] = s;
}

extern "C" void kernel_launch(void* const* d_in, const int* in_sizes, int n_in,
                              void* d_out, int out_size, void* d_ws, size_t ws_size,
                              hipStream_t stream)
{
    const float* pos = (const float*)d_in[0];
    float* out = (float*)d_out;
    float* ws  = (float*)d_ws;    // needs CHUNKS * NPTS * 3 * 4 B = 6.3 MB

    dim3 grid1(NPTS / BLOCK, CHUNKS);   // 32 x 64 = 2048 blocks, 8/CU
    nbody_partial<<<grid1, dim3(BLOCK), 0, stream>>>(pos, ws);

    dim3 grid2(NPTS * 3 / BLOCK);       // 96 blocks
    nbody_reduce<<<grid2, dim3(BLOCK), 0, stream>>>(ws, out);
}

// Round 9
// 31.977 us; speedup vs baseline: 1.2276x; 1.0615x over previous
//
#include <hip/hip_runtime.h>

#define NPTS   8192
#define BLOCK  256
#define CHUNKS 64
#define JT     (NPTS / CHUNKS)   // 128 j's per block-chunk

// Phase 1: block (bx, by) computes, for its 256 i's, the partial force over
// j in [by*JT, (by+1)*JT); coalesced stores to ws, no atomics.
// R8 change vs R3 (minimal diff): explicit 4-pair SoA batching inside the
// body — all r2 chains, then all rsq's, then all accumulates — so each wave
// has ~12 independent ops between a rsq and its consumer (dep-stall relief).
__global__ __launch_bounds__(BLOCK) void nbody_partial(
    const float* __restrict__ pos, float* __restrict__ ws)
{
    const int tid = threadIdx.x;
    const int i   = blockIdx.x * BLOCK + tid;
    const int j0  = blockIdx.y * JT;

    const float xi = pos[i * 3 + 0];
    const float yi = pos[i * 3 + 1];
    const float zi = pos[i * 3 + 2];

    float fx = 0.0f, fy = 0.0f, fz = 0.0f;

    const float4* __restrict__ pos4 = (const float4*)pos;

#pragma unroll 2
    for (int g = 0; g < JT / 4; ++g) {
        const int base = (j0 / 4 + g) * 3;       // float4 index (uniform)
        const float4 a = pos4[base + 0];
        const float4 b = pos4[base + 1];
        const float4 c = pos4[base + 2];

        const float px[4] = {a.x, a.w, b.z, c.y};
        const float py[4] = {a.y, b.x, b.w, c.z};
        const float pz[4] = {a.z, b.y, c.x, c.w};

        float dx[4], dy[4], dz[4], r2[4], w[4];

        // Phase A: 4 independent diff + r2 chains (static indices -> regs)
#pragma unroll
        for (int k = 0; k < 4; ++k) {
            dx[k] = xi - px[k];
            dy[k] = yi - py[k];
            dz[k] = zi - pz[k];
            r2[k] = fmaf(dz[k], dz[k],
                    fmaf(dy[k], dy[k],
                    fmaf(dx[k], dx[k], 1e-12f)));
        }

        // Phase B: 4 independent rsq -> w = r^-3 chains
#pragma unroll
        for (int k = 0; k < 4; ++k) {
            const float ir = __builtin_amdgcn_rsqf(r2[k]);
            w[k] = ir * ir * ir;
        }

        // Phase C: 4 accumulations
#pragma unroll
        for (int k = 0; k < 4; ++k) {
            fx = fmaf(dx[k], w[k], fx);
            fy = fmaf(dy[k], w[k], fy);
            fz = fmaf(dz[k], w[k], fz);
        }
    }

    float* o = ws + ((size_t)blockIdx.y * NPTS + i) * 3;
    o[0] = fx; o[1] = fy; o[2] = fz;
}

// Phase 2: out[e] = sum over chunks of ws[ch][e]. Fully coalesced.
__global__ __launch_bounds__(BLOCK) void nbody_reduce(
    const float* __restrict__ ws, float* __restrict__ out)
{
    const int e = blockIdx.x * BLOCK + threadIdx.x;   // 0 .. NPTS*3-1
    float s = 0.0f;
#pragma unroll 16
    for (int ch = 0; ch < CHUNKS; ++ch)
        s += ws[(size_t)ch * NPTS * 3 + e];
    out[e] = s;
}

extern "C" void kernel_launch(void* const* d_in, const int* in_sizes, int n_in,
                              void* d_out, int out_size, void* d_ws, size_t ws_size,
                              hipStream_t stream)
{
    const float* pos = (const float*)d_in[0];
    float* out = (float*)d_out;
    float* ws  = (float*)d_ws;    // needs CHUNKS * NPTS * 3 * 4 B = 6.3 MB

    dim3 grid1(NPTS / BLOCK, CHUNKS);   // 32 x 64 = 2048 blocks, 8/CU
    nbody_partial<<<grid1, dim3(BLOCK), 0, stream>>>(pos, ws);

    dim3 grid2(NPTS * 3 / BLOCK);       // 96 blocks
    nbody_reduce<<<grid2, dim3(BLOCK), 0, stream>>>(ws, out);
}